// Round 19
// baseline (34.867 us; speedup 1.0000x reference)
//
#include <hip/hip_runtime.h>
#include <hip/hip_bf16.h>

#define TWO_PI 6.283185307179586f

typedef __attribute__((ext_vector_type(8))) short short8;
typedef __attribute__((ext_vector_type(4))) float f32x4;
typedef __attribute__((ext_vector_type(2))) float f32x2;
typedef __attribute__((ext_vector_type(4))) unsigned u32x4;
struct __align__(4) U3 { unsigned x, y, z; };

// Half-up bf16 rounding (ties-up). NOTE (R5 post-mortem): v_cvt_pk_bf16_f32
// TRUNCATES on gfx950 — its -0.5ulp mean bias scaled by the 16384-term logJ
// sum to absmax 44. Half-up's bias is P(tie)=2^-16 -> logJ shift ~3e-4: safe.
__device__ __forceinline__ unsigned pack2_bf16(float lo, float hi) {
    return __builtin_amdgcn_perm(__float_as_uint(hi) + 0x8000u,
                                 __float_as_uint(lo) + 0x8000u,
                                 0x07060302u);
}
__device__ __forceinline__ float bf162f(unsigned short h) {
    return __uint_as_float(((unsigned)h) << 16);
}
__device__ __forceinline__ float exp2_raw(float z) {
    float e; asm("v_exp_f32 %0, %1" : "=v"(e) : "v"(z)); return e;
}
__device__ __forceinline__ float log2_raw(float z) {
    float e; asm("v_log_f32 %0, %1" : "=v"(e) : "v"(z)); return e;
}
// HW sin/cos take REVOLUTIONS; x in [0,2pi) -> rev in [0,1): no reduction.
__device__ __forceinline__ float sin_rev(float rv) {
    float s; asm("v_sin_f32 %0, %1" : "=v"(s) : "v"(rv)); return s;
}
__device__ __forceinline__ float cos_rev(float rv) {
    float c; asm("v_cos_f32 %0, %1" : "=v"(c) : "v"(rv)); return c;
}
__device__ __forceinline__ float rcp_raw(float z) {
    float r; asm("v_rcp_f32 %0, %1" : "=v"(r) : "v"(z)); return r;
}
#define INV_2PI 0.15915494309189535f
#define LOG2E   1.4426950408889634f
#define LN2     0.6931471805599453f

// Paired gelu, EXP-FREE (R19): gelu = 0.5a(1+tanh(u)), u=0.79788456(a+0.044715a^3),
// tanh via Pade u(945+105u^2+u^4)/(945+420u^2+15u^4). Realized |u|<=~1.5
// (conv1 pre-acts bounded by 0.1-scale weights) -> Pade err <1e-6, equi-
// oscillating (no bias). Removes 2 quarter-rate v_exp per pair; rcp stays.
__device__ __forceinline__ unsigned gelu2_pack(float x0, float x1) {
    f32x2 a  = {x0, x1};
    f32x2 a2 = a * a;
    f32x2 tp = __builtin_elementwise_fma(
        a2, (f32x2){0.035677408f, 0.035677408f},   // 0.79788456*0.044715
        (f32x2){0.7978845608f, 0.7978845608f});
    f32x2 u  = a * tp;
    f32x2 u2 = u * u;
    f32x2 q  = __builtin_elementwise_fma(
        u2, u2 + (f32x2){105.f, 105.f}, (f32x2){945.f, 945.f});
    f32x2 num = u * q;
    f32x2 r  = __builtin_elementwise_fma(
        u2, (f32x2){15.f, 15.f}, (f32x2){420.f, 420.f});
    f32x2 den = __builtin_elementwise_fma(u2, r, (f32x2){945.f, 945.f});
    f32x2 rc = {rcp_raw(den.x), rcp_raw(den.y)};
    f32x2 T  = num * rc;
    f32x2 ha = a * (f32x2){0.5f, 0.5f};
    f32x2 g  = __builtin_elementwise_fma(ha, T, ha);
    return pack2_bf16(g.x, g.y);
}

// ---- weight prep (40 blocks, 1 elem/thread) ----
// ws[0..1024)      : w1t[32 o][32 k]; col o<16 -> ch 2o, o>=16 -> ch 2(o-16)+1.
//                    K-REMAP: k = 8*lg + 2*i + in covers tap (3*lg + i), i<3,
//                    lg<3; other slots zero -> P1 A-gather = contiguous 3 words.
// ws[1024..10240)  : wt[9 q][4 cb][32 o][8 ci]  (o>=25 zero), ch = 8cb+ci
__global__ void prep_weights(const float* __restrict__ w1,
                             const float* __restrict__ w2,
                             unsigned short* __restrict__ ws) {
    int t = blockIdx.x * 256 + threadIdx.x;
    if (t >= 10240) return;
    float f = 0.0f;
    if (t < 1024) {
        int o = t >> 5, k = t & 31;
        int ch = (o < 16) ? 2 * o : 2 * (o - 16) + 1;
        int lg = k >> 3, j = k & 7;
        int i  = j >> 1, in = j & 1;
        if (lg < 3 && i < 3) {
            int tap = 3 * lg + i;                  // tap q = di*3+dj, di=lg, dj=i
            f = w1[ch * 18 + in * 9 + tap];
        }
    } else {
        int idx = t - 1024;
        int q  = idx >> 10;
        int r  = idx & 1023;
        int cb = r >> 8;
        int o  = (r >> 3) & 31;
        int ci = r & 7;
        if (o < 25) f = w2[(o * 32 + cb * 8 + ci) * 9 + q];
    }
    unsigned a = __float_as_uint(f);   // full RNE (runs once)
    ws[t] = (unsigned short)((a + 0x7fffu + ((a >> 16) & 1)) >> 16);
}

// ---- logJ final reduction: 4096 per-wave partials -> 16 sums (no atomics) ----
__global__ void reduce_logj(const float* __restrict__ partial,
                            float* __restrict__ logj) {
    const int bb = threadIdx.x >> 6, i = threadIdx.x & 63;
    const float* p = partial + bb * 256;
    float s = p[i] + p[64 + i] + p[128 + i] + p[192 + i];
    #pragma unroll
    for (int off = 32; off > 0; off >>= 1)
        s += __shfl_down(s, off);
    if (i == 0) logj[bb] = s;
}

#define NO2 30     // net_out pixel stride in shorts (15 words: odd bank walk)
#define NPOS 578   // h positions: 17 rows x 34 cols (strip 16x32 + halo 1)

// B=16, L=256. Block = 16x32 strip, 512 threads (8 waves). R13/R15 structure
// (R14's 10-wave variant regressed: VALU issue already ~72% saturated).
// logJ via per-(block,wave) partial stores to d_ws — NO atomics (R10 lesson:
// 4096 same-line atomicAdds serialized ~25us at the LLC regardless of compute).
__global__ __launch_bounds__(512, 6) void plaq_fused(
    const float* __restrict__ x,
    const float* __restrict__ b1, const float* __restrict__ b2,
    const unsigned short* __restrict__ ws,
    float* __restrict__ fx_out, float* __restrict__ partial)
{
    const int tid = threadIdx.x;
    const int bb  = blockIdx.z;
    const int gi0 = blockIdx.y * 16;
    const int gj0 = blockIdx.x * 32;

    __shared__ float xs[20][36];                    // pixel (r-2, c-2); 2880 B
    __shared__ __align__(16) union {
        unsigned cssn[720];                         // packed (cos,sin) bf16
        unsigned short net_out[128 * NO2];          // conv2 @ active px (7680 B)
    } sm;
    // h: pos = hpi*34 + hpj (pixel (hpi-1, hpj-1)), pos in [0,578).
    // 16B slot = 8 ch; slot = pos*4 + (ch>>3); swizzle slot ^= (slot>>3)&7.
    __shared__ __align__(16) unsigned hs_u32[NPOS * 16];   // 36992 B

    const float* xb = x + (size_t)bb * 65536;

    // ---- P0: stage x strip + cos/sin, PAIRED (1 frozen + 1 passive px per
    // thread -> one divergence-free sincos, single pass over 360 pairs) ----
    if (tid < 360) {
        int r  = tid / 18, cp = tid - (tid / 18) * 18;
        int c0 = 2 * cp;
        int gr  = (gi0 + r - 2) & 255;
        int gc0 = (gj0 + c0 - 2) & 255;          // even -> gc1 = gc0+1, no wrap
        float2 v = *(const float2*)(xb + gr * 256 + gc0);
        *(float2*)&xs[r][c0] = v;
        int f = (gr ^ gc0) & 1;                  // 1 -> c0 frozen, else c1
        float xv = f ? v.x : v.y;
        float rv = xv * INV_2PI;
        unsigned pk = pack2_bf16(cos_rev(rv), sin_rev(rv));
        uint2 out;
        out.x = f ? pk : 0x3f80u;
        out.y = f ? 0x3f80u : pk;
        *(uint2*)&sm.cssn[r * 36 + c0] = out;
    }
    __syncthreads();

    const int w  = tid >> 6;      // wave 0..7
    const int l  = tid & 63;
    const int lg = l >> 4;        // k-slice group
    const int lr = l & 15;        // A-row / B-col within 16x16 MFMA tile

    const int sw   = (blockIdx.x + blockIdx.y + blockIdx.z) & 7;
    const int role = (w - sw) & 7;              // 0,1 = spline waves

    // ---- early pass-through (role>=2): stores drain under P1/P2 compute ----
    if (role >= 2) {
        const int idx3   = role - 2;            // 0..5
        const int off_id = idx3 >> 1;           // 0,1,2 -> (di,dj)=(0,1),(1,0),(1,1)
        const int sub    = ((idx3 & 1) << 6) + l;   // 0..127
        const int oi = 2 * (sub >> 4) + ((off_id + 1) >> 1);
        const int oj = 2 * (sub & 15) + (off_id == 1 ? 0 : 1);
        fx_out[(size_t)bb * 65536 + (gi0 + oi) * 256 + gj0 + oj] = xs[oi + 2][oj + 2];
    }

    // ---- P1: conv1 via MFMA (M=578 pos, N=32 ch, K=18) + GELU -> hs ----
    {
        short8 bf0 = *(const short8*)(ws + (lr * 32 + lg * 8));        // ch 2lr
        short8 bf1 = *(const short8*)(ws + ((16 + lr) * 32 + lg * 8)); // ch 2lr+1
        const float bias0 = b1[2 * lr], bias1 = b1[2 * lr + 1];

        // K-remap: lane's 4 A-words = window row lg, cols 0..2, + zero word.
        // lg==3 reads garbage words (x0 weights); addr stays in the union.
        const int rowoff = lg * 36;

        // read base: rb = hpi*36 + hpj = pr + 2*(pr/34); incremental (+128/iter)
        int pr  = w * 16 + lr;
        int hpj = pr % 34;
        int rb  = pr + 2 * (pr / 34) + rowoff;

        // store bases: slot = mt*64 + 16lg + 4r + (lr>>2); (slot>>3)&7 is
        // mt-invariant = (lg<<1)|(r>>1). Byte addr = swz(slot)*16 + (lr&3)*4;
        // mt steps by 8 -> +8192 B immediate per unrolled iteration.
        unsigned sb[4];
        #pragma unroll
        for (int r = 0; r < 4; ++r) {
            int low6 = lg * 16 + r * 4 + (lr >> 2);
            int xorv = (lg << 1) | (r >> 1);
            sb[r] = (unsigned)(((low6 ^ xorv) * 16) + (lr & 3) * 4 + w * 1024);
        }
        char* hsb = (char*)hs_u32;

        #pragma unroll
        for (int it = 0; it < 5; ++it) {
            if (it < 4 || w < 5) {           // mt = w + 8*it < 37
                U3 w3 = *(const U3*)&sm.cssn[rb];
                u32x4 aw = {w3.x, w3.y, w3.z, 0u};
                short8 af = __builtin_bit_cast(short8, aw);

                f32x4 d0 = (f32x4){bias0, bias0, bias0, bias0};
                f32x4 d1 = (f32x4){bias1, bias1, bias1, bias1};
                d0 = __builtin_amdgcn_mfma_f32_16x16x32_bf16(af, bf0, d0, 0, 0, 0);
                d1 = __builtin_amdgcn_mfma_f32_16x16x32_bf16(af, bf1, d1, 0, 0, 0);

                #pragma unroll
                for (int r = 0; r < 4; ++r) {
                    // ps = (w+8it)*16+4lg+r; guard only it==4 tail (ps<578)
                    if (it < 4 || w < 4 || (lg == 0 && r < 2)) {
                        unsigned pk = gelu2_pack(d0[r], d1[r]);
                        *(unsigned*)(hsb + sb[r] + it * 8192) = pk;
                    }
                }
                hpj += 26; rb += 134;                  // pr += 128
                if (hpj >= 34) { hpj -= 34; rb += 2; } // row wrap
            }
        }
    }
    __syncthreads();

    // ---- P2: conv2 via MFMA at ACTIVE pixels only (M=128, N=25, K=288) ----
    {
        const unsigned short* wt = ws + 1024;   // [9][4][32][8]
        const int sb2 = w * 272 + lr * 8 + lg;  // slot base for px (2w, 2lr)
        float bv0 = b2[lr];
        float bv1 = (lr < 9) ? b2[16 + lr] : 0.0f;
        f32x4 acc0 = (f32x4){bv0, bv0, bv0, bv0};
        f32x4 acc1 = (f32x4){bv1, bv1, bv1, bv1};

        #pragma unroll
        for (int di = 0; di < 3; ++di) {
            #pragma unroll
            for (int dj = 0; dj < 3; ++dj) {
                int q = di * 3 + dj;
                short8 b0  = *(const short8*)(wt + ((q * 4 + lg) * 32 + lr) * 8);
                short8 b1v = *(const short8*)(wt + ((q * 4 + lg) * 32 + 16 + lr) * 8);
                int slot = sb2 + di * 136 + dj * 4;
                slot ^= (slot >> 3) & 7;
                short8 af = *(const short8*)&hs_u32[slot * 4];
                acc0 = __builtin_amdgcn_mfma_f32_16x16x32_bf16(af, b0,  acc0, 0, 0, 0);
                acc1 = __builtin_amdgcn_mfma_f32_16x16x32_bf16(af, b1v, acc1, 0, 0, 0);
            }
        }
        #pragma unroll
        for (int r = 0; r < 4; ++r) {
            int p = 16 * w + 4 * lg + r;        // active-pixel index stored
            unsigned pk = pack2_bf16(acc0[r], acc1[r]);   // lo=acc0, hi=acc1
            sm.net_out[p * NO2 + lr] = (unsigned short)pk;
            if (lr < 9) sm.net_out[p * NO2 + 16 + lr] = (unsigned short)(pk >> 16);
        }
    }
    __syncthreads();

    // ---- P3: spline on TWO waves (128 active px); others already done ----
    if (role < 2) {
        const int a  = role * 64 + l;           // active idx 0..127
        const int oi = 2 * (a >> 4), oj = 2 * (a & 15);
        const float xv = xs[oi + 2][oj + 2];

        // paired net_out reads: 12 x ds_read_b32 + 1 x b16 (base is 4B-aligned:
        // a*NO2 shorts = a*60 bytes)
        float no[25];
        {
            const unsigned* p32 = (const unsigned*)&sm.net_out[a * NO2];
            #pragma unroll
            for (int j = 0; j < 12; ++j) {
                unsigned u = p32[j];
                no[2 * j]     = __uint_as_float(u << 16);
                no[2 * j + 1] = __uint_as_float(u & 0xffff0000u);
            }
            no[24] = bf162f(sm.net_out[a * NO2 + 24]);
        }

        // softmax WITHOUT max-sub: |net_out| <~10 (0.05-scale weights), exp2
        // safe in f32. Both softmaxes computed together (paired f32x2 muls).
        float ev[8], eh[8], sa[9];
        #pragma unroll
        for (int k = 0; k < 8; ++k) {
            f32x2 z = (f32x2){no[k], no[8 + k]} * (f32x2){LOG2E, LOG2E};
            ev[k] = exp2_raw(z.x);
            eh[k] = exp2_raw(z.y);
        }
        f32x2 s2 = {ev[0], eh[0]};
        #pragma unroll
        for (int k = 1; k < 8; ++k) s2 += (f32x2){ev[k], eh[k]};
        float invx = TWO_PI * rcp_raw(s2.x);
        float invy = TWO_PI * rcp_raw(s2.y);

        // softplus, paired; overflow guard dropped (|v|<~10 << 80 bound)
        #pragma unroll
        for (int k = 0; k < 4; ++k) {
            f32x2 z = (f32x2){no[16 + 2 * k], no[17 + 2 * k]} * (f32x2){LOG2E, LOG2E};
            f32x2 e = {exp2_raw(z.x), exp2_raw(z.y)};
            f32x2 d = e + (f32x2){1.0f, 1.0f};
            sa[2 * k]     = LN2 * log2_raw(d.x);
            sa[2 * k + 1] = LN2 * log2_raw(d.y);
        }
        sa[8] = sa[0];

        float x1 = xv;   // x in [0,2pi) by construction

        // fused bin-select on RAW prefixes: kx[k] <= x1  <=>  p_k <= T with
        // T = x1*sum_x/2pi. Never materializes kx[]/ky[]. An idx flip at an
        // exact knot is harmless: the RQS is C1-continuous at knots.
        float T = x1 * s2.x * INV_2PI;
        f32x2 pq = {ev[0], eh[0]};             // running prefixes p_k, q_k
        float px = 0.f, evx = ev[0], qy = 0.f, ehy = eh[0];
        float dk = sa[0], dk1 = sa[1];
        #pragma unroll
        for (int k = 1; k < 8; ++k) {
            bool c = (pq.x <= T);
            px  = c ? pq.x      : px;
            evx = c ? ev[k]     : evx;
            qy  = c ? pq.y      : qy;
            ehy = c ? eh[k]     : ehy;
            dk  = c ? sa[k]     : dk;
            dk1 = c ? sa[k + 1] : dk1;
            if (k < 7) pq += (f32x2){ev[k], eh[k]};
        }
        float xk = px  * invx;
        float wk = evx * invx;                  // = kx[idx+1]-kx[idx]
        float yk = qy  * invy;
        float hk = ehy * invy;

        float rw  = rcp_raw(wk);                // shared: sl and th
        float sl  = hk * rw;
        float th  = (x1 - xk) * rw;
        float th1 = th * (1.f - th);
        float den = sl + (dk1 + dk - 2.f * sl) * th1;
        float rd  = rcp_raw(den);               // shared: fx1 and deriv
        float fx1 = __builtin_fmaf(hk * (sl * th * th + dk * th1), rd, yk);
        float omt = 1.f - th;
        float deriv = sl * sl * (dk1 * th * th + 2.f * sl * th1 + dk * omt * omt)
                      * rd * rd;
        float logd2 = log2_raw(deriv);          // LN2 applied after reduce

        // |t| << 2pi (18-sigma bound) -> single-step wrap each side
        float m = fx1 + no[24];
        if (m >= TWO_PI) m -= TWO_PI;
        if (m < 0.f)     m += TWO_PI;

        fx_out[(size_t)bb * 65536 + (gi0 + oi) * 256 + gj0 + oj] = m;

        #pragma unroll
        for (int off = 32; off > 0; off >>= 1)
            logd2 += __shfl_down(logd2, off);
        if (l == 0) {
            // per-(block,role) slot: contention-free plain store (no atomics)
            int bid = (bb * 128 + blockIdx.y * 8 + blockIdx.x) * 2 + role;
            partial[bid] = LN2 * logd2;
        }
    }
}

extern "C" void kernel_launch(void* const* d_in, const int* in_sizes, int n_in,
                              void* d_out, int out_size, void* d_ws, size_t ws_size,
                              hipStream_t stream) {
    const float* x  = (const float*)d_in[0];
    const float* w1 = (const float*)d_in[4];
    const float* b1 = (const float*)d_in[5];
    const float* w2 = (const float*)d_in[6];
    const float* b2 = (const float*)d_in[7];

    float* fx_out = (float*)d_out;
    float* logj   = (float*)d_out + (size_t)16 * 256 * 256;
    unsigned short* ws = (unsigned short*)d_ws;
    float* partial = (float*)((char*)d_ws + 20480);   // 4096 floats

    prep_weights<<<40, 256, 0, stream>>>(w1, w2, ws);

    dim3 grid(8, 16, 16);   // (j-strips of 32, i-tiles of 16, batch)
    plaq_fused<<<grid, 512, 0, stream>>>(x, b1, b2, ws, fx_out, partial);

    reduce_logj<<<1, 1024, 0, stream>>>(partial, logj);
}

// Round 20
// 33.291 us; speedup vs baseline: 1.0473x; 1.0473x over previous
//
#include <hip/hip_runtime.h>
#include <hip/hip_bf16.h>

#define TWO_PI 6.283185307179586f

typedef __attribute__((ext_vector_type(8))) short short8;
typedef __attribute__((ext_vector_type(4))) float f32x4;
typedef __attribute__((ext_vector_type(2))) float f32x2;
typedef __attribute__((ext_vector_type(4))) unsigned u32x4;
struct __align__(4) U3 { unsigned x, y, z; };

// Half-up bf16 rounding (ties-up). NOTE (R5 post-mortem): v_cvt_pk_bf16_f32
// TRUNCATES on gfx950 — its -0.5ulp mean bias scaled by the 16384-term logJ
// sum to absmax 44. Half-up's bias is P(tie)=2^-16 -> logJ shift ~3e-4: safe.
__device__ __forceinline__ unsigned pack2_bf16(float lo, float hi) {
    return __builtin_amdgcn_perm(__float_as_uint(hi) + 0x8000u,
                                 __float_as_uint(lo) + 0x8000u,
                                 0x07060302u);
}
__device__ __forceinline__ float bf162f(unsigned short h) {
    return __uint_as_float(((unsigned)h) << 16);
}
__device__ __forceinline__ float exp2_raw(float z) {
    float e; asm("v_exp_f32 %0, %1" : "=v"(e) : "v"(z)); return e;
}
__device__ __forceinline__ float log2_raw(float z) {
    float e; asm("v_log_f32 %0, %1" : "=v"(e) : "v"(z)); return e;
}
// HW sin/cos take REVOLUTIONS; x in [0,2pi) -> rev in [0,1): no reduction.
__device__ __forceinline__ float sin_rev(float rv) {
    float s; asm("v_sin_f32 %0, %1" : "=v"(s) : "v"(rv)); return s;
}
__device__ __forceinline__ float cos_rev(float rv) {
    float c; asm("v_cos_f32 %0, %1" : "=v"(c) : "v"(rv)); return c;
}
__device__ __forceinline__ float rcp_raw(float z) {
    float r; asm("v_rcp_f32 %0, %1" : "=v"(r) : "v"(z)); return r;
}
#define INV_2PI 0.15915494309189535f
#define LOG2E   1.4426950408889634f
#define LN2     0.6931471805599453f

// Paired gelu (jax tanh-gelu == a*sigmoid(1.5957691*(a+0.044715 a^3))),
// f32x2 arithmetic -> v_pk_{mul,fma,add}_f32 on CDNA4; exp/rcp stay scalar.
// R19 lesson: KEEP the exp form — v_exp issues on the separate trans pipe
// (latency hidden under VALU work); a Pade tanh ADDING VALU ops regressed 4.7%.
__device__ __forceinline__ unsigned gelu2_pack(float x0, float x1) {
    f32x2 a  = {x0, x1};
    f32x2 a2 = a * a;
    f32x2 p  = __builtin_elementwise_fma(
        a2, (f32x2){-0.10295206f, -0.10295206f},
        (f32x2){-2.3022947928f, -2.3022947928f});
    f32x2 z  = a * p;
    f32x2 e  = {exp2_raw(z.x), exp2_raw(z.y)};
    f32x2 d  = e + (f32x2){1.0f, 1.0f};
    f32x2 rc = {rcp_raw(d.x), rcp_raw(d.y)};
    f32x2 g  = a * rc;
    return pack2_bf16(g.x, g.y);
}

// ---- weight prep (40 blocks, 1 elem/thread) ----
// ws[0..1024)      : w1t[32 o][32 k]; col o<16 -> ch 2o, o>=16 -> ch 2(o-16)+1.
//                    K-REMAP: k = 8*lg + 2*i + in covers tap (3*lg + i), i<3,
//                    lg<3; other slots zero -> P1 A-gather = contiguous 3 words.
// ws[1024..10240)  : wt[9 q][4 cb][32 o][8 ci]  (o>=25 zero), ch = 8cb+ci
__global__ void prep_weights(const float* __restrict__ w1,
                             const float* __restrict__ w2,
                             unsigned short* __restrict__ ws) {
    int t = blockIdx.x * 256 + threadIdx.x;
    if (t >= 10240) return;
    float f = 0.0f;
    if (t < 1024) {
        int o = t >> 5, k = t & 31;
        int ch = (o < 16) ? 2 * o : 2 * (o - 16) + 1;
        int lg = k >> 3, j = k & 7;
        int i  = j >> 1, in = j & 1;
        if (lg < 3 && i < 3) {
            int tap = 3 * lg + i;                  // tap q = di*3+dj, di=lg, dj=i
            f = w1[ch * 18 + in * 9 + tap];
        }
    } else {
        int idx = t - 1024;
        int q  = idx >> 10;
        int r  = idx & 1023;
        int cb = r >> 8;
        int o  = (r >> 3) & 31;
        int ci = r & 7;
        if (o < 25) f = w2[(o * 32 + cb * 8 + ci) * 9 + q];
    }
    unsigned a = __float_as_uint(f);   // full RNE (runs once)
    ws[t] = (unsigned short)((a + 0x7fffu + ((a >> 16) & 1)) >> 16);
}

// ---- logJ final reduction: 4096 per-wave partials -> 16 sums (no atomics) ----
__global__ void reduce_logj(const float* __restrict__ partial,
                            float* __restrict__ logj) {
    const int bb = threadIdx.x >> 6, i = threadIdx.x & 63;
    const float* p = partial + bb * 256;
    float s = p[i] + p[64 + i] + p[128 + i] + p[192 + i];
    #pragma unroll
    for (int off = 32; off > 0; off >>= 1)
        s += __shfl_down(s, off);
    if (i == 0) logj[bb] = s;
}

#define NO2 30     // net_out pixel stride in shorts (15 words: odd bank walk)
#define NPOS 578   // h positions: 17 rows x 34 cols (strip 16x32 + halo 1)

// B=16, L=256. Block = 16x32 strip, 512 threads (8 waves). R13/R15 structure
// (R14's 10-wave variant regressed: VALU issue already ~72% saturated).
// logJ via per-(block,wave) partial stores to d_ws — NO atomics (R10 lesson:
// 4096 same-line atomicAdds serialized ~25us at the LLC regardless of compute).
__global__ __launch_bounds__(512, 6) void plaq_fused(
    const float* __restrict__ x,
    const float* __restrict__ b1, const float* __restrict__ b2,
    const unsigned short* __restrict__ ws,
    float* __restrict__ fx_out, float* __restrict__ partial)
{
    const int tid = threadIdx.x;
    const int bb  = blockIdx.z;
    const int gi0 = blockIdx.y * 16;
    const int gj0 = blockIdx.x * 32;

    __shared__ float xs[20][36];                    // pixel (r-2, c-2); 2880 B
    __shared__ __align__(16) union {
        unsigned cssn[720];                         // packed (cos,sin) bf16
        unsigned short net_out[128 * NO2];          // conv2 @ active px (7680 B)
    } sm;
    // h: pos = hpi*34 + hpj (pixel (hpi-1, hpj-1)), pos in [0,578).
    // 16B slot = 8 ch; slot = pos*4 + (ch>>3); swizzle slot ^= (slot>>3)&7.
    __shared__ __align__(16) unsigned hs_u32[NPOS * 16];   // 36992 B

    const float* xb = x + (size_t)bb * 65536;

    // ---- P0: stage x strip + cos/sin, PAIRED (1 frozen + 1 passive px per
    // thread -> one divergence-free sincos, single pass over 360 pairs) ----
    if (tid < 360) {
        int r  = tid / 18, cp = tid - (tid / 18) * 18;
        int c0 = 2 * cp;
        int gr  = (gi0 + r - 2) & 255;
        int gc0 = (gj0 + c0 - 2) & 255;          // even -> gc1 = gc0+1, no wrap
        float2 v = *(const float2*)(xb + gr * 256 + gc0);
        *(float2*)&xs[r][c0] = v;
        int f = (gr ^ gc0) & 1;                  // 1 -> c0 frozen, else c1
        float xv = f ? v.x : v.y;
        float rv = xv * INV_2PI;
        unsigned pk = pack2_bf16(cos_rev(rv), sin_rev(rv));
        uint2 out;
        out.x = f ? pk : 0x3f80u;
        out.y = f ? 0x3f80u : pk;
        *(uint2*)&sm.cssn[r * 36 + c0] = out;
    }
    __syncthreads();

    const int w  = tid >> 6;      // wave 0..7
    const int l  = tid & 63;
    const int lg = l >> 4;        // k-slice group
    const int lr = l & 15;        // A-row / B-col within 16x16 MFMA tile

    const int sw   = (blockIdx.x + blockIdx.y + blockIdx.z) & 7;
    const int role = (w - sw) & 7;              // 0,1 = spline waves

    // ---- early pass-through (role>=2): stores drain under P1/P2 compute ----
    if (role >= 2) {
        const int idx3   = role - 2;            // 0..5
        const int off_id = idx3 >> 1;           // 0,1,2 -> (di,dj)=(0,1),(1,0),(1,1)
        const int sub    = ((idx3 & 1) << 6) + l;   // 0..127
        const int oi = 2 * (sub >> 4) + ((off_id + 1) >> 1);
        const int oj = 2 * (sub & 15) + (off_id == 1 ? 0 : 1);
        fx_out[(size_t)bb * 65536 + (gi0 + oi) * 256 + gj0 + oj] = xs[oi + 2][oj + 2];
    }

    // ---- P1: conv1 via MFMA (M=578 pos, N=32 ch, K=18) + GELU -> hs ----
    {
        short8 bf0 = *(const short8*)(ws + (lr * 32 + lg * 8));        // ch 2lr
        short8 bf1 = *(const short8*)(ws + ((16 + lr) * 32 + lg * 8)); // ch 2lr+1
        const float bias0 = b1[2 * lr], bias1 = b1[2 * lr + 1];

        // K-remap: lane's 4 A-words = window row lg, cols 0..2, + zero word.
        // lg==3 reads garbage words (x0 weights); addr stays in the union.
        const int rowoff = lg * 36;

        // read base: rb = hpi*36 + hpj = pr + 2*(pr/34); incremental (+128/iter)
        int pr  = w * 16 + lr;
        int hpj = pr % 34;
        int rb  = pr + 2 * (pr / 34) + rowoff;

        // store bases: slot = mt*64 + 16lg + 4r + (lr>>2); (slot>>3)&7 is
        // mt-invariant = (lg<<1)|(r>>1). Byte addr = swz(slot)*16 + (lr&3)*4;
        // mt steps by 8 -> +8192 B immediate per unrolled iteration.
        unsigned sb[4];
        #pragma unroll
        for (int r = 0; r < 4; ++r) {
            int low6 = lg * 16 + r * 4 + (lr >> 2);
            int xorv = (lg << 1) | (r >> 1);
            sb[r] = (unsigned)(((low6 ^ xorv) * 16) + (lr & 3) * 4 + w * 1024);
        }
        char* hsb = (char*)hs_u32;

        #pragma unroll
        for (int it = 0; it < 5; ++it) {
            if (it < 4 || w < 5) {           // mt = w + 8*it < 37
                U3 w3 = *(const U3*)&sm.cssn[rb];
                u32x4 aw = {w3.x, w3.y, w3.z, 0u};
                short8 af = __builtin_bit_cast(short8, aw);

                f32x4 d0 = (f32x4){bias0, bias0, bias0, bias0};
                f32x4 d1 = (f32x4){bias1, bias1, bias1, bias1};
                d0 = __builtin_amdgcn_mfma_f32_16x16x32_bf16(af, bf0, d0, 0, 0, 0);
                d1 = __builtin_amdgcn_mfma_f32_16x16x32_bf16(af, bf1, d1, 0, 0, 0);

                #pragma unroll
                for (int r = 0; r < 4; ++r) {
                    // ps = (w+8it)*16+4lg+r; guard only it==4 tail (ps<578)
                    if (it < 4 || w < 4 || (lg == 0 && r < 2)) {
                        unsigned pk = gelu2_pack(d0[r], d1[r]);
                        *(unsigned*)(hsb + sb[r] + it * 8192) = pk;
                    }
                }
                hpj += 26; rb += 134;                  // pr += 128
                if (hpj >= 34) { hpj -= 34; rb += 2; } // row wrap
            }
        }
    }
    __syncthreads();

    // ---- P2: conv2 via MFMA at ACTIVE pixels only (M=128, N=25, K=288) ----
    {
        const unsigned short* wt = ws + 1024;   // [9][4][32][8]
        const int sb2 = w * 272 + lr * 8 + lg;  // slot base for px (2w, 2lr)
        float bv0 = b2[lr];
        float bv1 = (lr < 9) ? b2[16 + lr] : 0.0f;
        f32x4 acc0 = (f32x4){bv0, bv0, bv0, bv0};
        f32x4 acc1 = (f32x4){bv1, bv1, bv1, bv1};

        #pragma unroll
        for (int di = 0; di < 3; ++di) {
            #pragma unroll
            for (int dj = 0; dj < 3; ++dj) {
                int q = di * 3 + dj;
                short8 b0  = *(const short8*)(wt + ((q * 4 + lg) * 32 + lr) * 8);
                short8 b1v = *(const short8*)(wt + ((q * 4 + lg) * 32 + 16 + lr) * 8);
                int slot = sb2 + di * 136 + dj * 4;
                slot ^= (slot >> 3) & 7;
                short8 af = *(const short8*)&hs_u32[slot * 4];
                acc0 = __builtin_amdgcn_mfma_f32_16x16x32_bf16(af, b0,  acc0, 0, 0, 0);
                acc1 = __builtin_amdgcn_mfma_f32_16x16x32_bf16(af, b1v, acc1, 0, 0, 0);
            }
        }
        #pragma unroll
        for (int r = 0; r < 4; ++r) {
            int p = 16 * w + 4 * lg + r;        // active-pixel index stored
            unsigned pk = pack2_bf16(acc0[r], acc1[r]);   // lo=acc0, hi=acc1
            sm.net_out[p * NO2 + lr] = (unsigned short)pk;
            if (lr < 9) sm.net_out[p * NO2 + 16 + lr] = (unsigned short)(pk >> 16);
        }
    }
    __syncthreads();

    // ---- P3: spline on TWO waves (128 active px); others already done ----
    if (role < 2) {
        const int a  = role * 64 + l;           // active idx 0..127
        const int oi = 2 * (a >> 4), oj = 2 * (a & 15);
        const float xv = xs[oi + 2][oj + 2];

        // paired net_out reads: 12 x ds_read_b32 + 1 x b16 (base is 4B-aligned:
        // a*NO2 shorts = a*60 bytes)
        float no[25];
        {
            const unsigned* p32 = (const unsigned*)&sm.net_out[a * NO2];
            #pragma unroll
            for (int j = 0; j < 12; ++j) {
                unsigned u = p32[j];
                no[2 * j]     = __uint_as_float(u << 16);
                no[2 * j + 1] = __uint_as_float(u & 0xffff0000u);
            }
            no[24] = bf162f(sm.net_out[a * NO2 + 24]);
        }

        // softmax WITHOUT max-sub: |net_out| <~10 (0.05-scale weights), exp2
        // safe in f32. Both softmaxes computed together (paired f32x2 muls).
        float ev[8], eh[8], sa[9];
        #pragma unroll
        for (int k = 0; k < 8; ++k) {
            f32x2 z = (f32x2){no[k], no[8 + k]} * (f32x2){LOG2E, LOG2E};
            ev[k] = exp2_raw(z.x);
            eh[k] = exp2_raw(z.y);
        }
        f32x2 s2 = {ev[0], eh[0]};
        #pragma unroll
        for (int k = 1; k < 8; ++k) s2 += (f32x2){ev[k], eh[k]};
        float invx = TWO_PI * rcp_raw(s2.x);
        float invy = TWO_PI * rcp_raw(s2.y);

        // softplus, paired; overflow guard dropped (|v|<~10 << 80 bound)
        #pragma unroll
        for (int k = 0; k < 4; ++k) {
            f32x2 z = (f32x2){no[16 + 2 * k], no[17 + 2 * k]} * (f32x2){LOG2E, LOG2E};
            f32x2 e = {exp2_raw(z.x), exp2_raw(z.y)};
            f32x2 d = e + (f32x2){1.0f, 1.0f};
            sa[2 * k]     = LN2 * log2_raw(d.x);
            sa[2 * k + 1] = LN2 * log2_raw(d.y);
        }
        sa[8] = sa[0];

        float x1 = xv;   // x in [0,2pi) by construction

        // fused bin-select on RAW prefixes: kx[k] <= x1  <=>  p_k <= T with
        // T = x1*sum_x/2pi. Never materializes kx[]/ky[]. An idx flip at an
        // exact knot is harmless: the RQS is C1-continuous at knots.
        float T = x1 * s2.x * INV_2PI;
        f32x2 pq = {ev[0], eh[0]};             // running prefixes p_k, q_k
        float px = 0.f, evx = ev[0], qy = 0.f, ehy = eh[0];
        float dk = sa[0], dk1 = sa[1];
        #pragma unroll
        for (int k = 1; k < 8; ++k) {
            bool c = (pq.x <= T);
            px  = c ? pq.x      : px;
            evx = c ? ev[k]     : evx;
            qy  = c ? pq.y      : qy;
            ehy = c ? eh[k]     : ehy;
            dk  = c ? sa[k]     : dk;
            dk1 = c ? sa[k + 1] : dk1;
            if (k < 7) pq += (f32x2){ev[k], eh[k]};
        }
        float xk = px  * invx;
        float wk = evx * invx;                  // = kx[idx+1]-kx[idx]
        float yk = qy  * invy;
        float hk = ehy * invy;

        float rw  = rcp_raw(wk);                // shared: sl and th
        float sl  = hk * rw;
        float th  = (x1 - xk) * rw;
        float th1 = th * (1.f - th);
        float den = sl + (dk1 + dk - 2.f * sl) * th1;
        float rd  = rcp_raw(den);               // shared: fx1 and deriv
        float fx1 = __builtin_fmaf(hk * (sl * th * th + dk * th1), rd, yk);
        float omt = 1.f - th;
        float deriv = sl * sl * (dk1 * th * th + 2.f * sl * th1 + dk * omt * omt)
                      * rd * rd;
        float logd2 = log2_raw(deriv);          // LN2 applied after reduce

        // |t| << 2pi (18-sigma bound) -> single-step wrap each side
        float m = fx1 + no[24];
        if (m >= TWO_PI) m -= TWO_PI;
        if (m < 0.f)     m += TWO_PI;

        fx_out[(size_t)bb * 65536 + (gi0 + oi) * 256 + gj0 + oj] = m;

        #pragma unroll
        for (int off = 32; off > 0; off >>= 1)
            logd2 += __shfl_down(logd2, off);
        if (l == 0) {
            // per-(block,role) slot: contention-free plain store (no atomics)
            int bid = (bb * 128 + blockIdx.y * 8 + blockIdx.x) * 2 + role;
            partial[bid] = LN2 * logd2;
        }
    }
}

extern "C" void kernel_launch(void* const* d_in, const int* in_sizes, int n_in,
                              void* d_out, int out_size, void* d_ws, size_t ws_size,
                              hipStream_t stream) {
    const float* x  = (const float*)d_in[0];
    const float* w1 = (const float*)d_in[4];
    const float* b1 = (const float*)d_in[5];
    const float* w2 = (const float*)d_in[6];
    const float* b2 = (const float*)d_in[7];

    float* fx_out = (float*)d_out;
    float* logj   = (float*)d_out + (size_t)16 * 256 * 256;
    unsigned short* ws = (unsigned short*)d_ws;
    float* partial = (float*)((char*)d_ws + 20480);   // 4096 floats

    prep_weights<<<40, 256, 0, stream>>>(w1, w2, ws);

    dim3 grid(8, 16, 16);   // (j-strips of 32, i-tiles of 16, batch)
    plaq_fused<<<grid, 512, 0, stream>>>(x, b1, b2, ws, fx_out, partial);

    reduce_logj<<<1, 1024, 0, stream>>>(partial, logj);
}